// Round 5
// baseline (462.963 us; speedup 1.0000x reference)
//
#include <hip/hip_runtime.h>

typedef unsigned short u16;
typedef unsigned int u32;
typedef __attribute__((ext_vector_type(4))) float f32x4;
typedef __attribute__((ext_vector_type(8))) short bf16x8;
typedef __attribute__((ext_vector_type(8))) u16 u16x8;
typedef __attribute__((ext_vector_type(4))) u16 u16x4;
typedef __attribute__((ext_vector_type(4))) u32 u32x4;

#define DEVI __device__ __forceinline__

constexpr int C_ = 512, S_ = 32768, L_ = 256, CTX_ = 768;

DEVI u16 f2b(float f) {  // fp32 -> bf16 RNE
    union { float f; unsigned u; } x; x.f = f;
    unsigned r = x.u + 0x7fffu + ((x.u >> 16) & 1u);
    return (u16)(r >> 16);
}

DEVI f32x4 mfma16(bf16x8 a, bf16x8 b, f32x4 c) {
    return __builtin_amdgcn_mfma_f32_16x16x32_bf16(a, b, c, 0, 0, 0);
}

DEVI void gload16(const void* g, void* l) {
    __builtin_amdgcn_global_load_lds(
        (const __attribute__((address_space(1))) void*)g,
        (__attribute__((address_space(3))) void*)l, 16, 0, 0);
}

DEVI u32 cvtpk(float lo, float hi) {  // word = (bf16(hi)<<16) | bf16(lo)
    u32 d;
    asm("v_cvt_pk_bf16_f32 %0, %1, %2" : "=v"(d) : "v"(lo), "v"(hi));
    return d;
}
DEVI void pl32(u32& a, u32& b) {
    asm volatile("v_permlane32_swap_b32 %0, %1" : "+v"(a), "+v"(b));
}
DEVI void pl16(u32& a, u32& b) {
    asm volatile("v_permlane16_swap_b32 %0, %1" : "+v"(a), "+v"(b));
}

// ---------------------------------------------------------------- weights cvt
__global__ __launch_bounds__(256) void cvt_w(
    const float* __restrict__ a0, const float* __restrict__ a1,
    const float* __restrict__ a2, const float* __restrict__ a3,
    u16* __restrict__ o0, u16* __restrict__ o1,
    u16* __restrict__ o2, u16* __restrict__ o3)
{
    int which = blockIdx.y;
    const float* src = which == 0 ? a0 : which == 1 ? a1 : which == 2 ? a2 : a3;
    u16* dst = which == 0 ? o0 : which == 1 ? o1 : which == 2 ? o2 : o3;
    int n4 = (which == 1 || which == 2) ? (512 * 768 / 4) : (512 * 512 / 4);
    int i = blockIdx.x * 256 + threadIdx.x;
    if (i < n4) {
        float4 v = ((const float4*)src)[i];
        u16x4 o; o[0] = f2b(v.x); o[1] = f2b(v.y); o[2] = f2b(v.z); o[3] = f2b(v.w);
        ((u16x4*)dst)[i] = o;
    }
}

// ---------------------------------------------------------------- GN stats
__global__ __launch_bounds__(256) void gn_partial(const float* __restrict__ x,
                                                  float* __restrict__ part)
{
    const int bg = blockIdx.y, blk = blockIdx.x, tid = threadIdx.x;
    const float* base = x + (size_t)bg * 64 * S_ + (size_t)blk * 1024 + tid * 4;
    float s1 = 0.f, s2 = 0.f;
    for (int c = 0; c < 64; ++c) {
        float4 v = *(const float4*)(base + (size_t)c * S_);
        s1 += v.x + v.y + v.z + v.w;
        s2 += v.x * v.x + v.y * v.y + v.z * v.z + v.w * v.w;
    }
    for (int m = 1; m < 64; m <<= 1) { s1 += __shfl_xor(s1, m); s2 += __shfl_xor(s2, m); }
    __shared__ float a1[4], a2[4];
    int w = tid >> 6, lane = tid & 63;
    if (lane == 0) { a1[w] = s1; a2[w] = s2; }
    __syncthreads();
    if (tid == 0) {
        part[(bg * 32 + blk) * 2 + 0] = a1[0] + a1[1] + a1[2] + a1[3];
        part[(bg * 32 + blk) * 2 + 1] = a2[0] + a2[1] + a2[2] + a2[3];
    }
}

__global__ __launch_bounds__(64) void gn_final(const float* __restrict__ part,
                                               float* __restrict__ stats)
{
    int bg = blockIdx.x, tid = threadIdx.x;
    float s1 = tid < 32 ? part[(bg * 32 + tid) * 2] : 0.f;
    float s2 = tid < 32 ? part[(bg * 32 + tid) * 2 + 1] : 0.f;
    for (int m = 1; m < 32; m <<= 1) { s1 += __shfl_xor(s1, m); s2 += __shfl_xor(s2, m); }
    if (tid == 0) {
        const float invN = 1.0f / (64.0f * (float)S_);
        float mu = s1 * invN, var = s2 * invN - mu * mu;
        stats[bg * 2] = mu;
        stats[bg * 2 + 1] = rsqrtf(var + 1e-5f);
    }
}

// ------------------------------------------- GN apply + transpose to (b,s,c) bf16
__global__ __launch_bounds__(256) void gn_apply(
    const float* __restrict__ x, const float* __restrict__ stats,
    const float* __restrict__ gw, const float* __restrict__ gb,
    u16* __restrict__ ht)
{
    __shared__ float tile[64][65];
    const int tid = threadIdx.x, sl = tid & 63, c4 = tid >> 6;
    const int s0 = blockIdx.x * 64, c0 = blockIdx.y * 64, b = blockIdx.z;
    const int bg = b * 8 + (c0 >> 6);
    const float mu = stats[bg * 2], rstd = stats[bg * 2 + 1];
#pragma unroll
    for (int i = 0; i < 16; ++i) {
        int cl = c4 * 16 + i;
        float wv = gw[c0 + cl], bv = gb[c0 + cl];
        float v = x[((size_t)(b * C_ + c0 + cl)) * S_ + s0 + sl];
        tile[sl][cl] = (v - mu) * rstd * wv + bv;
    }
    __syncthreads();
#pragma unroll
    for (int rep = 0; rep < 2; ++rep) {
        int task = rep * 256 + tid;
        int so = task >> 3, cb = task & 7;
        u16x8 o;
#pragma unroll
        for (int j = 0; j < 8; ++j) o[j] = f2b(tile[so][cb * 8 + j]);
        *(u16x8*)&ht[((size_t)(b * S_ + s0 + so)) * C_ + c0 + cb * 8] = o;
    }
}

// ---------------------------------------------------------------- LayerNorm(ctx)
__global__ __launch_bounds__(256) void ln_ctx(
    const float* __restrict__ ctx, const float* __restrict__ lw,
    const float* __restrict__ lb, u16* __restrict__ cn)
{
    const int row = blockIdx.x, tid = threadIdx.x;
    const float* p = ctx + (size_t)row * CTX_;
    float v0 = p[tid], v1 = p[tid + 256], v2 = p[tid + 512];
    float s1 = v0 + v1 + v2, s2 = v0 * v0 + v1 * v1 + v2 * v2;
    for (int m = 1; m < 64; m <<= 1) { s1 += __shfl_xor(s1, m); s2 += __shfl_xor(s2, m); }
    __shared__ float a1[4], a2[4];
    int w = tid >> 6, lane = tid & 63;
    if (lane == 0) { a1[w] = s1; a2[w] = s2; }
    __syncthreads();
    s1 = a1[0] + a1[1] + a1[2] + a1[3];
    s2 = a2[0] + a2[1] + a2[2] + a2[3];
    const float invN = 1.0f / 768.0f;
    float mu = s1 * invN, rstd = rsqrtf(s2 * invN - mu * mu + 1e-5f);
    u16* o = cn + (size_t)row * CTX_;
    o[tid]       = f2b((v0 - mu) * rstd * lw[tid]       + lb[tid]);
    o[tid + 256] = f2b((v1 - mu) * rstd * lw[tid + 256] + lb[tid + 256]);
    o[tid + 512] = f2b((v2 - mu) * rstd * lw[tid + 512] + lb[tid + 512]);
}

// ---------------------------------------------------------------- NT-GEMM
// acc = mfma(Bfrag, Afrag): col(lane&15) = m-row, rows(g*4+i) = n-rows.
// => per lane: m fixed (r), 4 CONSECUTIVE n per (n-step) -> vector epilogues.
// Double-buffered (32KB LDS), 1 barrier/iter, XCD-swizzled grid.
// SWAP: m-tile from blockIdx.y (consecutive ids share the A m-tile).
// MODE 0: bf16 out[m*ldo + n..n+3] = (acc + bias[n]) * scale   (uint2)
// MODE 2: f32  out[m*ldo + n..n+3] = acc + bias[m] + resid     (float4)
// MODE 3: z==0 -> like MODE0 to outp (K proj); z==1 -> V-scatter to outp2
template <int MODE, bool SWAP>
__global__ __launch_bounds__(256, 4) void gemm_nt(
    const u16* __restrict__ A, const u16* __restrict__ Bp,
    const float* __restrict__ bias, void* __restrict__ outp,
    const float* __restrict__ resid, int K, int ldo,
    size_t aStride, size_t bStride, size_t oStride, float scale,
    const u16* __restrict__ Bp2, const float* __restrict__ bias2,
    void* __restrict__ outp2)
{
    __shared__ __align__(16) u16 lA[2][4096];
    __shared__ __align__(16) u16 lB[2][4096];
    const int tid = threadIdx.x;
    const int w = tid >> 6, lane = tid & 63;
    const int g = lane >> 4, r = lane & 15;

    // XCD-aware bijective swizzle of the per-z (x,y) grid (nxy % 8 == 0).
    const int nx = gridDim.x, nxy = nx * gridDim.y;
    const int raw = blockIdx.x + nx * blockIdx.y;
    const int tile = (raw & 7) * (nxy >> 3) + (raw >> 3);
    const int bx = tile % nx, by = tile / nx;
    const int m0 = (SWAP ? by : bx) * 128, n0 = (SWAP ? bx : by) * 128;
    const int z = blockIdx.z;
    A += (size_t)z * aStride;
    const u16* Bsel = Bp;
    if constexpr (MODE == 3) { if (z) Bsel = Bp2; }
    Bsel += (size_t)z * bStride;

    // staging source pre-swizzle (rule #21: linear LDS dest, permuted source)
    const int l8 = lane & 7, lh = lane >> 3;
    const int u_ = l8 ^ lh;                 // slot-at-dest ^ row&7
    const int mro = (lh << 1) + (u_ >> 2);  // row offset within 16-row chunk
    const int kco = (u_ & 3) * 8;           // k offset (elements) within 32
    const int wr = w >> 1, wc = w & 1;
    const int nt = K >> 5;

    f32x4 acc[4][4];
#pragma unroll
    for (int m = 0; m < 4; ++m)
#pragma unroll
        for (int n = 0; n < 4; ++n) acc[m][n] = f32x4{0.f, 0.f, 0.f, 0.f};

#define STAGE_T(t, bi_) {                                                      \
    size_t ko_ = (size_t)((t) * 32 + kco);                                     \
    _Pragma("unroll")                                                          \
    for (int j = 0; j < 2; ++j) {                                              \
        int grow_ = w * 32 + j * 16 + mro;                                     \
        gload16(A + (size_t)(m0 + grow_) * K + ko_,                            \
                &lA[bi_][(w * 16 + j * 8) << 6]);                              \
        gload16(Bsel + (size_t)(n0 + grow_) * K + ko_,                         \
                &lB[bi_][(w * 16 + j * 8) << 6]);                              \
    } }

    STAGE_T(0, 0);
    __syncthreads();

    for (int t = 0; t < nt; ++t) {
        const int cur = t & 1;
        if (t + 1 < nt) STAGE_T(t + 1, cur ^ 1);
        bf16x8 af[4], bf_[4];
#pragma unroll
        for (int m = 0; m < 4; ++m) {
            int row = wr * 32 + m * 8 + (r >> 1);
            int slot = (((r & 1) << 2) + g) ^ ((r >> 1) & 7);
            af[m] = *(const bf16x8*)&lA[cur][(row << 6) + (slot << 3)];
        }
#pragma unroll
        for (int n = 0; n < 4; ++n) {
            int row = wc * 32 + n * 8 + (r >> 1);
            int slot = (((r & 1) << 2) + g) ^ ((r >> 1) & 7);
            bf_[n] = *(const bf16x8*)&lB[cur][(row << 6) + (slot << 3)];
        }
#pragma unroll
        for (int m = 0; m < 4; ++m)
#pragma unroll
            for (int n = 0; n < 4; ++n)
                acc[m][n] = mfma16(bf_[n], af[m], acc[m][n]);  // swapped: col=m, rows=n
        __syncthreads();
    }
#undef STAGE_T

    if constexpr (MODE == 0) {
        u16* ob = (u16*)outp + (size_t)z * oStride;
#pragma unroll
        for (int m = 0; m < 4; ++m) {
            int gm = m0 + wr * 64 + m * 16 + r;
#pragma unroll
            for (int n = 0; n < 4; ++n) {
                int gn0 = n0 + wc * 64 + n * 16 + g * 4;
                float4 bn = *(const float4*)&bias[gn0];
                u32 w0 = cvtpk(acc[m][n][0] * scale + bn.x * scale,
                               acc[m][n][1] * scale + bn.y * scale);
                u32 w1 = cvtpk(acc[m][n][2] * scale + bn.z * scale,
                               acc[m][n][3] * scale + bn.w * scale);
                *(uint2*)&ob[(size_t)gm * ldo + gn0] = make_uint2(w0, w1);
            }
        }
    } else if constexpr (MODE == 2) {
        float* of = (float*)outp + (size_t)z * oStride;
        const float* rs = resid + (size_t)z * oStride;
#pragma unroll
        for (int m = 0; m < 4; ++m) {
            int gm = m0 + wr * 64 + m * 16 + r;
            float bm = bias[gm];
#pragma unroll
            for (int n = 0; n < 4; ++n) {
                int gn0 = n0 + wc * 64 + n * 16 + g * 4;
                size_t idx = (size_t)gm * ldo + gn0;
                float4 rv = *(const float4*)&rs[idx];
                float4 o4;
                o4.x = acc[m][n][0] + bm + rv.x;
                o4.y = acc[m][n][1] + bm + rv.y;
                o4.z = acc[m][n][2] + bm + rv.z;
                o4.w = acc[m][n][3] + bm + rv.w;
                *(float4*)&of[idx] = o4;
            }
        }
    } else if constexpr (MODE == 3) {
        if (z == 0) {  // K projection: (b*l, o) bf16
            u16* ob = (u16*)outp;
#pragma unroll
            for (int m = 0; m < 4; ++m) {
                int gm = m0 + wr * 64 + m * 16 + r;
#pragma unroll
                for (int n = 0; n < 4; ++n) {
                    int gn0 = n0 + wc * 64 + n * 16 + g * 4;
                    float4 bn = *(const float4*)&bias[gn0];
                    u32 w0 = cvtpk(acc[m][n][0] + bn.x, acc[m][n][1] + bn.y);
                    u32 w1 = cvtpk(acc[m][n][2] + bn.z, acc[m][n][3] + bn.w);
                    *(uint2*)&ob[(size_t)gm * ldo + gn0] = make_uint2(w0, w1);
                }
            }
        } else {       // V projection scattered to (b,h,e,l) bf16
            u16* ob = (u16*)outp2;
#pragma unroll
            for (int m = 0; m < 4; ++m) {
                int gm = m0 + wr * 64 + m * 16 + r;  // ctx row = b*256 + l
                int bb = gm >> 8, l = gm & 255;
#pragma unroll
                for (int n = 0; n < 4; ++n) {
                    int gn0 = n0 + wc * 64 + n * 16 + g * 4;
#pragma unroll
                    for (int i = 0; i < 4; ++i)
                        ob[((size_t)(bb * 512 + gn0 + i)) * 256 + l] =
                            f2b(acc[m][n][i] + bias2[gn0 + i]);
                }
            }
        }
    }
}

// ---------------------------------------------------------------- attention
// Swapped-QK^T: lane holds P[s = lane&15][l in regs]. K staged in LDS (32KB),
// V read direct from L2 (32KB/head, cache-resident). PV operand-swapped so the
// output has 4 consecutive e per lane -> 8B stores.
// grid: (S/128, B*NH). block 256 (4 waves, 32 s-rows each).
__global__ __launch_bounds__(256, 4) void attn_kernel(
    const u16* __restrict__ q, const u16* __restrict__ kk,
    const u16* __restrict__ vv, u16* __restrict__ ao)
{
    __shared__ __align__(16) u16 sm[16384];
    const int tid = threadIdx.x;
    const int w = tid >> 6, lane = tid & 63;
    const int g = lane >> 4, r = lane & 15;
    const int bh = blockIdx.y, b = bh >> 3, h = bh & 7;
    const int s0 = blockIdx.x * 128;

    {   // stage K (b,l,h*64+e) rows -> sm[l*64 + swz]
        const u16* kbase = kk + ((size_t)b * L_) * C_ + h * 64;
#pragma unroll
        for (int j = 0; j < 8; ++j) {
            int idx = j * 256 + tid;
            int l = idx >> 3, ch = idx & 7;
            u16x8 val = *(const u16x8*)(kbase + (size_t)l * C_ + ch * 8);
            *(u16x8*)&sm[l * 64 + ((ch ^ (l & 7)) << 3)] = val;
        }
    }

    // Q fragments straight from global (read-once)
    const int sw = s0 + w * 32;
    bf16x8 qf[2][2];
#pragma unroll
    for (int m = 0; m < 2; ++m)
#pragma unroll
        for (int kt = 0; kt < 2; ++kt)
            qf[m][kt] = *(const bf16x8*)(q + ((size_t)(b * S_ + sw + m * 16 + r)) * C_
                                         + h * 64 + kt * 32 + g * 8);
    __syncthreads();

    // QK^T swapped: accs[m][n][i] = P[s = m*16 + r][l = n*16 + g*4 + i]
    f32x4 accs[2][16];
#pragma unroll
    for (int m = 0; m < 2; ++m)
#pragma unroll
        for (int n = 0; n < 16; ++n) accs[m][n] = f32x4{0.f, 0.f, 0.f, 0.f};
    __builtin_amdgcn_s_setprio(1);
#pragma unroll
    for (int n = 0; n < 16; ++n) {
#pragma unroll
        for (int kt = 0; kt < 2; ++kt) {
            int c = kt * 4 + g;  // e-chunk index
            bf16x8 kf = *(const bf16x8*)&sm[(n * 16 + r) * 64 + ((c ^ (r & 7)) << 3)];
#pragma unroll
            for (int m = 0; m < 2; ++m) accs[m][n] = mfma16(kf, qf[m][kt], accs[m][n]);
        }
    }
    __builtin_amdgcn_s_setprio(0);

    // softmax: in-lane over 64 values, cross-lane over the 4 lanes sharing r
    float inv[2];
#pragma unroll
    for (int m = 0; m < 2; ++m) {
        float mx = accs[m][0][0];
#pragma unroll
        for (int n = 0; n < 16; ++n)
#pragma unroll
            for (int i = 0; i < 4; ++i) mx = fmaxf(mx, accs[m][n][i]);
        mx = fmaxf(mx, __shfl_xor(mx, 16));
        mx = fmaxf(mx, __shfl_xor(mx, 32));
        float sum = 0.f;
#pragma unroll
        for (int n = 0; n < 16; ++n)
#pragma unroll
            for (int i = 0; i < 4; ++i) {
                float e = __expf(accs[m][n][i] - mx);
                accs[m][n][i] = e; sum += e;
            }
        sum += __shfl_xor(sum, 16);
        sum += __shfl_xor(sum, 32);
        inv[m] = 1.0f / sum;
    }

    // PV: per l-chunk c, repack P in-register into fragments, then MFMA.
    // Operand-swapped: acco[m][n]: col(r) = s, rows(g*4+i) = e.
    f32x4 acco[2][4];
#pragma unroll
    for (int m = 0; m < 2; ++m)
#pragma unroll
        for (int n = 0; n < 4; ++n) acco[m][n] = f32x4{0.f, 0.f, 0.f, 0.f};

    const u16* vbase = vv + ((size_t)bh * 64) * 256;
#pragma unroll
    for (int c = 0; c < 8; ++c) {
        bf16x8 pa[2];
#pragma unroll
        for (int m = 0; m < 2; ++m) {
            u32 x0 = cvtpk(accs[m][2 * c][0] * inv[m], accs[m][2 * c][1] * inv[m]);
            u32 x1 = cvtpk(accs[m][2 * c][2] * inv[m], accs[m][2 * c][3] * inv[m]);
            u32 y0 = cvtpk(accs[m][2 * c + 1][0] * inv[m], accs[m][2 * c + 1][1] * inv[m]);
            u32 y1 = cvtpk(accs[m][2 * c + 1][2] * inv[m], accs[m][2 * c + 1][3] * inv[m]);
            pl32(x0, y0);
            pl32(x1, y1);
            pl16(x0, y0);
            pl16(x1, y1);
            u32x4 pw; pw[0] = x0; pw[1] = x1; pw[2] = y0; pw[3] = y1;
            pa[m] = *(bf16x8*)&pw;
        }
        bf16x8 vf[4];
#pragma unroll
        for (int n = 0; n < 4; ++n)
            vf[n] = *(const bf16x8*)(vbase + ((size_t)(n * 16 + r)) * 256 + (c * 4 + g) * 8);
        __builtin_amdgcn_s_setprio(1);
#pragma unroll
        for (int m = 0; m < 2; ++m)
#pragma unroll
            for (int n = 0; n < 4; ++n)
                acco[m][n] = mfma16(vf[n], pa[m], acco[m][n]);  // col=s, rows=e
        __builtin_amdgcn_s_setprio(0);
    }

    // write attention output as (b, s, c=h*64+e) bf16, 8B per store
#pragma unroll
    for (int m = 0; m < 2; ++m) {
        const size_t rowb = ((size_t)(b * S_ + sw + m * 16 + r)) * C_ + h * 64;
#pragma unroll
        for (int n = 0; n < 4; ++n) {
            u32 w0 = cvtpk(acco[m][n][0], acco[m][n][1]);
            u32 w1 = cvtpk(acco[m][n][2], acco[m][n][3]);
            *(uint2*)&ao[rowb + n * 16 + g * 4] = make_uint2(w0, w1);
        }
    }
}

// ---------------------------------------------------------------- launch
extern "C" void kernel_launch(void* const* d_in, const int* in_sizes, int n_in,
                              void* d_out, int out_size, void* d_ws, size_t ws_size,
                              hipStream_t stream)
{
    (void)in_sizes; (void)n_in; (void)out_size; (void)ws_size;
    const float* x    = (const float*)d_in[0];
    const float* ctx  = (const float*)d_in[1];
    const float* gn_w = (const float*)d_in[2];
    const float* gn_b = (const float*)d_in[3];
    const float* ln_w = (const float*)d_in[4];
    const float* ln_b = (const float*)d_in[5];
    const float* q_w  = (const float*)d_in[6];
    const float* q_b  = (const float*)d_in[7];
    const float* k_w  = (const float*)d_in[8];
    const float* k_b  = (const float*)d_in[9];
    const float* v_w  = (const float*)d_in[10];
    const float* v_b  = (const float*)d_in[11];
    const float* p_w  = (const float*)d_in[12];
    const float* p_b  = (const float*)d_in[13];
    float* out = (float*)d_out;

    char* ws = (char*)d_ws;
    constexpr size_t WS_WQ   = 0;
    constexpr size_t WS_WK   = WS_WQ + (size_t)512 * 512 * 2;
    constexpr size_t WS_WV   = WS_WK + (size_t)512 * 768 * 2;
    constexpr size_t WS_WP   = WS_WV + (size_t)512 * 768 * 2;
    constexpr size_t WS_PART = WS_WP + (size_t)512 * 512 * 2;
    constexpr size_t WS_STAT = WS_PART + (size_t)16 * 64 * 2 * 4;
    constexpr size_t WS_CTXN = WS_STAT + 256;
    constexpr size_t WS_K    = WS_CTXN + (size_t)512 * 768 * 2;
    constexpr size_t WS_V    = WS_K + (size_t)2 * 8 * 256 * 64 * 2;
    constexpr size_t WS_Q    = WS_V + (size_t)2 * 8 * 256 * 64 * 2;
    constexpr size_t WS_H    = WS_Q + (size_t)2 * 32768 * 512 * 2;

    u16* wq = (u16*)(ws + WS_WQ);
    u16* wk = (u16*)(ws + WS_WK);
    u16* wv = (u16*)(ws + WS_WV);
    u16* wp = (u16*)(ws + WS_WP);
    float* part  = (float*)(ws + WS_PART);
    float* stats = (float*)(ws + WS_STAT);
    u16* ctxn = (u16*)(ws + WS_CTXN);
    u16* kt   = (u16*)(ws + WS_K);
    u16* vt   = (u16*)(ws + WS_V);
    u16* qt   = (u16*)(ws + WS_Q);
    u16* ht   = (u16*)(ws + WS_H);
    u16* ao   = ht;  // h dead after Q-GEMM; reuse for attention output

    const size_t bsc = (size_t)S_ * C_;  // per-batch (s,c)/(c,s) stride

    cvt_w<<<dim3(384, 4), 256, 0, stream>>>(q_w, k_w, v_w, p_w, wq, wk, wv, wp);
    gn_partial<<<dim3(32, 16), 256, 0, stream>>>(x, part);
    gn_final<<<16, 64, 0, stream>>>(part, stats);
    gn_apply<<<dim3(512, 8, 2), 256, 0, stream>>>(x, stats, gn_w, gn_b, ht);
    ln_ctx<<<512, 256, 0, stream>>>(ctx, ln_w, ln_b, ctxn);
    // Q = h . Wq^T (scale folded), out (b,s,o) bf16. SWAP grid: consecutive
    // ids share the ht m-tile -> same XCD after swizzle.
    gemm_nt<0, true><<<dim3(4, 256, 2), 256, 0, stream>>>(
        ht, wq, q_b, qt, nullptr, 512, 512, bsc, 0, bsc, 0.125f,
        nullptr, nullptr, nullptr);
    // K,V = ctxn . W^T in one launch (z selects)
    gemm_nt<3, false><<<dim3(4, 4, 2), 256, 0, stream>>>(
        ctxn, wk, k_b, kt, nullptr, 768, 512, 0, 0, 0, 1.0f,
        wv, v_b, vt);
    attn_kernel<<<dim3(256, 16), 256, 0, stream>>>(qt, kt, vt, ao);
    // out = Wp . ao^T + bias + x (fp32, (b,c,s)). Consecutive ids share the
    // ao n-tile -> same XCD after swizzle.
    gemm_nt<2, false><<<dim3(4, 256, 2), 256, 0, stream>>>(
        wp, ao, p_b, out, x, 512, S_, 0, bsc, bsc, 1.0f,
        nullptr, nullptr, nullptr);
}

// Round 6
// 282.120 us; speedup vs baseline: 1.6410x; 1.6410x over previous
//
#include <hip/hip_runtime.h>

typedef unsigned short u16;
typedef unsigned int u32;
typedef __attribute__((ext_vector_type(4))) float f32x4;
typedef __attribute__((ext_vector_type(8))) short bf16x8;
typedef __attribute__((ext_vector_type(8))) u16 u16x8;
typedef __attribute__((ext_vector_type(4))) u16 u16x4;
typedef __attribute__((ext_vector_type(4))) u32 u32x4;

#define DEVI __device__ __forceinline__

constexpr int C_ = 512, S_ = 32768, L_ = 256, CTX_ = 768;

DEVI u16 f2b(float f) {  // fp32 -> bf16 RNE
    union { float f; unsigned u; } x; x.f = f;
    unsigned r = x.u + 0x7fffu + ((x.u >> 16) & 1u);
    return (u16)(r >> 16);
}

DEVI f32x4 mfma16(bf16x8 a, bf16x8 b, f32x4 c) {
    return __builtin_amdgcn_mfma_f32_16x16x32_bf16(a, b, c, 0, 0, 0);
}

DEVI void gload16(const void* g, void* l) {
    __builtin_amdgcn_global_load_lds(
        (const __attribute__((address_space(1))) void*)g,
        (__attribute__((address_space(3))) void*)l, 16, 0, 0);
}

DEVI u32 cvtpk(float lo, float hi) {  // word = (bf16(hi)<<16) | bf16(lo)
    u32 d;
    asm("v_cvt_pk_bf16_f32 %0, %1, %2" : "=v"(d) : "v"(lo), "v"(hi));
    return d;
}
DEVI void pl32(u32& a, u32& b) {
    asm volatile("v_permlane32_swap_b32 %0, %1" : "+v"(a), "+v"(b));
}
DEVI void pl16(u32& a, u32& b) {
    asm volatile("v_permlane16_swap_b32 %0, %1" : "+v"(a), "+v"(b));
}

// ---------------------------------------------------------------- weights cvt
__global__ __launch_bounds__(256) void cvt_w(
    const float* __restrict__ a0, const float* __restrict__ a1,
    const float* __restrict__ a2, const float* __restrict__ a3,
    u16* __restrict__ o0, u16* __restrict__ o1,
    u16* __restrict__ o2, u16* __restrict__ o3)
{
    int which = blockIdx.y;
    const float* src = which == 0 ? a0 : which == 1 ? a1 : which == 2 ? a2 : a3;
    u16* dst = which == 0 ? o0 : which == 1 ? o1 : which == 2 ? o2 : o3;
    int n4 = (which == 1 || which == 2) ? (512 * 768 / 4) : (512 * 512 / 4);
    int i = blockIdx.x * 256 + threadIdx.x;
    if (i < n4) {
        float4 v = ((const float4*)src)[i];
        u16x4 o; o[0] = f2b(v.x); o[1] = f2b(v.y); o[2] = f2b(v.z); o[3] = f2b(v.w);
        ((u16x4*)dst)[i] = o;
    }
}

// ---------------------------------------------------------------- GN stats
__global__ __launch_bounds__(256) void gn_partial(const float* __restrict__ x,
                                                  float* __restrict__ part)
{
    const int bg = blockIdx.y, blk = blockIdx.x, tid = threadIdx.x;
    const float* base = x + (size_t)bg * 64 * S_ + (size_t)blk * 1024 + tid * 4;
    float s1 = 0.f, s2 = 0.f;
    for (int c = 0; c < 64; ++c) {
        float4 v = *(const float4*)(base + (size_t)c * S_);
        s1 += v.x + v.y + v.z + v.w;
        s2 += v.x * v.x + v.y * v.y + v.z * v.z + v.w * v.w;
    }
    for (int m = 1; m < 64; m <<= 1) { s1 += __shfl_xor(s1, m); s2 += __shfl_xor(s2, m); }
    __shared__ float a1[4], a2[4];
    int w = tid >> 6, lane = tid & 63;
    if (lane == 0) { a1[w] = s1; a2[w] = s2; }
    __syncthreads();
    if (tid == 0) {
        part[(bg * 32 + blk) * 2 + 0] = a1[0] + a1[1] + a1[2] + a1[3];
        part[(bg * 32 + blk) * 2 + 1] = a2[0] + a2[1] + a2[2] + a2[3];
    }
}

__global__ __launch_bounds__(64) void gn_final(const float* __restrict__ part,
                                               float* __restrict__ stats)
{
    int bg = blockIdx.x, tid = threadIdx.x;
    float s1 = tid < 32 ? part[(bg * 32 + tid) * 2] : 0.f;
    float s2 = tid < 32 ? part[(bg * 32 + tid) * 2 + 1] : 0.f;
    for (int m = 1; m < 32; m <<= 1) { s1 += __shfl_xor(s1, m); s2 += __shfl_xor(s2, m); }
    if (tid == 0) {
        const float invN = 1.0f / (64.0f * (float)S_);
        float mu = s1 * invN, var = s2 * invN - mu * mu;
        stats[bg * 2] = mu;
        stats[bg * 2 + 1] = rsqrtf(var + 1e-5f);
    }
}

// ------------------------------------------- GN apply + transpose to (b,s,c) bf16
__global__ __launch_bounds__(256) void gn_apply(
    const float* __restrict__ x, const float* __restrict__ stats,
    const float* __restrict__ gw, const float* __restrict__ gb,
    u16* __restrict__ ht)
{
    __shared__ float tile[64][65];
    const int tid = threadIdx.x, sl = tid & 63, c4 = tid >> 6;
    const int s0 = blockIdx.x * 64, c0 = blockIdx.y * 64, b = blockIdx.z;
    const int bg = b * 8 + (c0 >> 6);
    const float mu = stats[bg * 2], rstd = stats[bg * 2 + 1];
#pragma unroll
    for (int i = 0; i < 16; ++i) {
        int cl = c4 * 16 + i;
        float wv = gw[c0 + cl], bv = gb[c0 + cl];
        float v = x[((size_t)(b * C_ + c0 + cl)) * S_ + s0 + sl];
        tile[sl][cl] = (v - mu) * rstd * wv + bv;
    }
    __syncthreads();
#pragma unroll
    for (int rep = 0; rep < 2; ++rep) {
        int task = rep * 256 + tid;
        int so = task >> 3, cb = task & 7;
        u16x8 o;
#pragma unroll
        for (int j = 0; j < 8; ++j) o[j] = f2b(tile[so][cb * 8 + j]);
        *(u16x8*)&ht[((size_t)(b * S_ + s0 + so)) * C_ + c0 + cb * 8] = o;
    }
}

// ---------------------------------------------------------------- LayerNorm(ctx)
__global__ __launch_bounds__(256) void ln_ctx(
    const float* __restrict__ ctx, const float* __restrict__ lw,
    const float* __restrict__ lb, u16* __restrict__ cn)
{
    const int row = blockIdx.x, tid = threadIdx.x;
    const float* p = ctx + (size_t)row * CTX_;
    float v0 = p[tid], v1 = p[tid + 256], v2 = p[tid + 512];
    float s1 = v0 + v1 + v2, s2 = v0 * v0 + v1 * v1 + v2 * v2;
    for (int m = 1; m < 64; m <<= 1) { s1 += __shfl_xor(s1, m); s2 += __shfl_xor(s2, m); }
    __shared__ float a1[4], a2[4];
    int w = tid >> 6, lane = tid & 63;
    if (lane == 0) { a1[w] = s1; a2[w] = s2; }
    __syncthreads();
    s1 = a1[0] + a1[1] + a1[2] + a1[3];
    s2 = a2[0] + a2[1] + a2[2] + a2[3];
    const float invN = 1.0f / 768.0f;
    float mu = s1 * invN, rstd = rsqrtf(s2 * invN - mu * mu + 1e-5f);
    u16* o = cn + (size_t)row * CTX_;
    o[tid]       = f2b((v0 - mu) * rstd * lw[tid]       + lb[tid]);
    o[tid + 256] = f2b((v1 - mu) * rstd * lw[tid + 256] + lb[tid + 256]);
    o[tid + 512] = f2b((v2 - mu) * rstd * lw[tid + 512] + lb[tid + 512]);
}

// ---------------------------------------------------------------- NT-GEMM
// acc = mfma(Bfrag, Afrag): col(lane&15) = m-row, rows(g*4+i) = n-rows.
// => per lane: m fixed (r), 4 CONSECUTIVE n per (n-step) -> vector epilogues.
// Double-buffered (32KB LDS), 1 barrier/iter, XCD-swizzled grid.
// SWAP: m-tile from blockIdx.y (consecutive ids share the A m-tile).
// MODE 0: bf16 out[m*ldo + n..n+3] = (acc + bias[n]) * scale   (uint2)
// MODE 2: f32  out[m*ldo + n..n+3] = acc + bias[m] + resid     (float4)
// MODE 3: z==0 -> like MODE0 to outp (K proj); z==1 -> V-scatter to outp2
template <int MODE, bool SWAP>
__global__ __launch_bounds__(256, 4) void gemm_nt(
    const u16* __restrict__ A, const u16* __restrict__ Bp,
    const float* __restrict__ bias, void* __restrict__ outp,
    const float* __restrict__ resid, int K, int ldo,
    size_t aStride, size_t bStride, size_t oStride, float scale,
    const u16* __restrict__ Bp2, const float* __restrict__ bias2,
    void* __restrict__ outp2)
{
    __shared__ __align__(16) u16 lA[2][4096];
    __shared__ __align__(16) u16 lB[2][4096];
    const int tid = threadIdx.x;
    const int w = tid >> 6, lane = tid & 63;
    const int g = lane >> 4, r = lane & 15;

    // XCD-aware bijective swizzle of the per-z (x,y) grid (nxy % 8 == 0).
    const int nx = gridDim.x, nxy = nx * gridDim.y;
    const int raw = blockIdx.x + nx * blockIdx.y;
    const int tile = (raw & 7) * (nxy >> 3) + (raw >> 3);
    const int bx = tile % nx, by = tile / nx;
    const int m0 = (SWAP ? by : bx) * 128, n0 = (SWAP ? bx : by) * 128;
    const int z = blockIdx.z;
    A += (size_t)z * aStride;
    const u16* Bsel = Bp;
    if constexpr (MODE == 3) { if (z) Bsel = Bp2; }
    Bsel += (size_t)z * bStride;

    // staging source pre-swizzle (rule #21: linear LDS dest, permuted source)
    const int l8 = lane & 7, lh = lane >> 3;
    const int u_ = l8 ^ lh;                 // slot-at-dest ^ row&7
    const int mro = (lh << 1) + (u_ >> 2);  // row offset within 16-row chunk
    const int kco = (u_ & 3) * 8;           // k offset (elements) within 32
    const int wr = w >> 1, wc = w & 1;
    const int nt = K >> 5;

    f32x4 acc[4][4];
#pragma unroll
    for (int m = 0; m < 4; ++m)
#pragma unroll
        for (int n = 0; n < 4; ++n) acc[m][n] = f32x4{0.f, 0.f, 0.f, 0.f};

#define STAGE_T(t, bi_) {                                                      \
    size_t ko_ = (size_t)((t) * 32 + kco);                                     \
    _Pragma("unroll")                                                          \
    for (int j = 0; j < 2; ++j) {                                              \
        int grow_ = w * 32 + j * 16 + mro;                                     \
        gload16(A + (size_t)(m0 + grow_) * K + ko_,                            \
                &lA[bi_][(w * 16 + j * 8) << 6]);                              \
        gload16(Bsel + (size_t)(n0 + grow_) * K + ko_,                         \
                &lB[bi_][(w * 16 + j * 8) << 6]);                              \
    } }

    STAGE_T(0, 0);
    __syncthreads();

    for (int t = 0; t < nt; ++t) {
        const int cur = t & 1;
        if (t + 1 < nt) STAGE_T(t + 1, cur ^ 1);
        bf16x8 af[4], bf_[4];
#pragma unroll
        for (int m = 0; m < 4; ++m) {
            int row = wr * 32 + m * 8 + (r >> 1);
            int slot = (((r & 1) << 2) + g) ^ ((r >> 1) & 7);
            af[m] = *(const bf16x8*)&lA[cur][(row << 6) + (slot << 3)];
        }
#pragma unroll
        for (int n = 0; n < 4; ++n) {
            int row = wc * 32 + n * 8 + (r >> 1);
            int slot = (((r & 1) << 2) + g) ^ ((r >> 1) & 7);
            bf_[n] = *(const bf16x8*)&lB[cur][(row << 6) + (slot << 3)];
        }
#pragma unroll
        for (int m = 0; m < 4; ++m)
#pragma unroll
            for (int n = 0; n < 4; ++n)
                acc[m][n] = mfma16(bf_[n], af[m], acc[m][n]);  // swapped: col=m, rows=n
        __syncthreads();
    }
#undef STAGE_T

    if constexpr (MODE == 0) {
        u16* ob = (u16*)outp + (size_t)z * oStride;
#pragma unroll
        for (int m = 0; m < 4; ++m) {
            int gm = m0 + wr * 64 + m * 16 + r;
#pragma unroll
            for (int n = 0; n < 4; ++n) {
                int gn0 = n0 + wc * 64 + n * 16 + g * 4;
                float4 bn = *(const float4*)&bias[gn0];
                u32 w0 = cvtpk(acc[m][n][0] * scale + bn.x * scale,
                               acc[m][n][1] * scale + bn.y * scale);
                u32 w1 = cvtpk(acc[m][n][2] * scale + bn.z * scale,
                               acc[m][n][3] * scale + bn.w * scale);
                *(uint2*)&ob[(size_t)gm * ldo + gn0] = make_uint2(w0, w1);
            }
        }
    } else if constexpr (MODE == 2) {
        float* of = (float*)outp + (size_t)z * oStride;
        const float* rs = resid + (size_t)z * oStride;
#pragma unroll
        for (int m = 0; m < 4; ++m) {
            int gm = m0 + wr * 64 + m * 16 + r;
            float bm = bias[gm];
#pragma unroll
            for (int n = 0; n < 4; ++n) {
                int gn0 = n0 + wc * 64 + n * 16 + g * 4;
                size_t idx = (size_t)gm * ldo + gn0;
                float4 rv = *(const float4*)&rs[idx];
                float4 o4;
                o4.x = acc[m][n][0] + bm + rv.x;
                o4.y = acc[m][n][1] + bm + rv.y;
                o4.z = acc[m][n][2] + bm + rv.z;
                o4.w = acc[m][n][3] + bm + rv.w;
                *(float4*)&of[idx] = o4;
            }
        }
    } else if constexpr (MODE == 3) {
        if (z == 0) {  // K projection: (b*l, o) bf16
            u16* ob = (u16*)outp;
#pragma unroll
            for (int m = 0; m < 4; ++m) {
                int gm = m0 + wr * 64 + m * 16 + r;
#pragma unroll
                for (int n = 0; n < 4; ++n) {
                    int gn0 = n0 + wc * 64 + n * 16 + g * 4;
                    float4 bn = *(const float4*)&bias[gn0];
                    u32 w0 = cvtpk(acc[m][n][0] + bn.x, acc[m][n][1] + bn.y);
                    u32 w1 = cvtpk(acc[m][n][2] + bn.z, acc[m][n][3] + bn.w);
                    *(uint2*)&ob[(size_t)gm * ldo + gn0] = make_uint2(w0, w1);
                }
            }
        } else {       // V projection scattered to (b,h,e,l) bf16
            u16* ob = (u16*)outp2;
#pragma unroll
            for (int m = 0; m < 4; ++m) {
                int gm = m0 + wr * 64 + m * 16 + r;  // ctx row = b*256 + l
                int bb = gm >> 8, l = gm & 255;
#pragma unroll
                for (int n = 0; n < 4; ++n) {
                    int gn0 = n0 + wc * 64 + n * 16 + g * 4;
#pragma unroll
                    for (int i = 0; i < 4; ++i)
                        ob[((size_t)(bb * 512 + gn0 + i)) * 256 + l] =
                            f2b(acc[m][n][i] + bias2[gn0 + i]);
                }
            }
        }
    }
}

// ---------------------------------------------------------------- attention
// Swapped-QK^T: lane holds P[s = lane&15][l in regs]. K AND V staged in LDS
// (64 KB) -- each block reads them once, coalesced; keeps L2 free for the
// Q/ao streams (R5 lesson: direct-global V thrashed L2 -> 4-8x HBM traffic).
// PV operand-swapped: output has 4 consecutive e per lane -> 8B stores.
// grid: (S/128, B*NH). block 256 (4 waves, 32 s-rows each).
__global__ __launch_bounds__(256, 2) void attn_kernel(
    const u16* __restrict__ q, const u16* __restrict__ kk,
    const u16* __restrict__ vv, u16* __restrict__ ao)
{
    __shared__ __align__(16) u16 sm[32768];
    const int tid = threadIdx.x;
    const int w = tid >> 6, lane = tid & 63;
    const int g = lane >> 4, r = lane & 15;
    const int bh = blockIdx.y, b = bh >> 3, h = bh & 7;
    const int s0 = blockIdx.x * 128;

    {   // stage K (b,l,h*64+e) rows -> sm[l*64 + swz]
        const u16* kbase = kk + ((size_t)b * L_) * C_ + h * 64;
#pragma unroll
        for (int j = 0; j < 8; ++j) {
            int idx = j * 256 + tid;
            int l = idx >> 3, ch = idx & 7;
            u16x8 val = *(const u16x8*)(kbase + (size_t)l * C_ + ch * 8);
            *(u16x8*)&sm[l * 64 + ((ch ^ (l & 7)) << 3)] = val;
        }
        // stage V (b,h,e,l) rows -> sm[16384 + e*256 + swz]
        const u16* vbase = vv + ((size_t)bh * 64) * 256;
#pragma unroll
        for (int j = 0; j < 8; ++j) {
            int idx = j * 256 + tid;
            int e = idx >> 5, ch = idx & 31;
            u16x8 val = *(const u16x8*)(vbase + (size_t)e * 256 + ch * 8);
            *(u16x8*)&sm[16384 + e * 256 + ((ch ^ (e & 7)) << 3)] = val;
        }
    }

    // Q fragments straight from global (read-once)
    const int sw = s0 + w * 32;
    bf16x8 qf[2][2];
#pragma unroll
    for (int m = 0; m < 2; ++m)
#pragma unroll
        for (int kt = 0; kt < 2; ++kt)
            qf[m][kt] = *(const bf16x8*)(q + ((size_t)(b * S_ + sw + m * 16 + r)) * C_
                                         + h * 64 + kt * 32 + g * 8);
    __syncthreads();

    // QK^T swapped: accs[m][n][i] = P[s = m*16 + r][l = n*16 + g*4 + i]
    f32x4 accs[2][16];
#pragma unroll
    for (int m = 0; m < 2; ++m)
#pragma unroll
        for (int n = 0; n < 16; ++n) accs[m][n] = f32x4{0.f, 0.f, 0.f, 0.f};
    __builtin_amdgcn_s_setprio(1);
#pragma unroll
    for (int n = 0; n < 16; ++n) {
#pragma unroll
        for (int kt = 0; kt < 2; ++kt) {
            int c = kt * 4 + g;  // e-chunk index
            bf16x8 kf = *(const bf16x8*)&sm[(n * 16 + r) * 64 + ((c ^ (r & 7)) << 3)];
#pragma unroll
            for (int m = 0; m < 2; ++m) accs[m][n] = mfma16(kf, qf[m][kt], accs[m][n]);
        }
    }
    __builtin_amdgcn_s_setprio(0);

    // softmax: in-lane over 64 values, cross-lane over the 4 lanes sharing r
    float inv[2];
#pragma unroll
    for (int m = 0; m < 2; ++m) {
        float mx = accs[m][0][0];
#pragma unroll
        for (int n = 0; n < 16; ++n)
#pragma unroll
            for (int i = 0; i < 4; ++i) mx = fmaxf(mx, accs[m][n][i]);
        mx = fmaxf(mx, __shfl_xor(mx, 16));
        mx = fmaxf(mx, __shfl_xor(mx, 32));
        float sum = 0.f;
#pragma unroll
        for (int n = 0; n < 16; ++n)
#pragma unroll
            for (int i = 0; i < 4; ++i) {
                float e = __expf(accs[m][n][i] - mx);
                accs[m][n][i] = e; sum += e;
            }
        sum += __shfl_xor(sum, 16);
        sum += __shfl_xor(sum, 32);
        inv[m] = 1.0f / sum;
    }

    // PV: per l-chunk c, repack P in-register into fragments, then MFMA.
    // Operand-swapped: acco[m][n]: col(r) = s, rows(g*4+i) = e.
    f32x4 acco[2][4];
#pragma unroll
    for (int m = 0; m < 2; ++m)
#pragma unroll
        for (int n = 0; n < 4; ++n) acco[m][n] = f32x4{0.f, 0.f, 0.f, 0.f};

#pragma unroll
    for (int c = 0; c < 8; ++c) {
        bf16x8 pa[2];
#pragma unroll
        for (int m = 0; m < 2; ++m) {
            u32 x0 = cvtpk(accs[m][2 * c][0] * inv[m], accs[m][2 * c][1] * inv[m]);
            u32 x1 = cvtpk(accs[m][2 * c][2] * inv[m], accs[m][2 * c][3] * inv[m]);
            u32 y0 = cvtpk(accs[m][2 * c + 1][0] * inv[m], accs[m][2 * c + 1][1] * inv[m]);
            u32 y1 = cvtpk(accs[m][2 * c + 1][2] * inv[m], accs[m][2 * c + 1][3] * inv[m]);
            pl32(x0, y0);
            pl32(x1, y1);
            pl16(x0, y0);
            pl16(x1, y1);
            u32x4 pw; pw[0] = x0; pw[1] = x1; pw[2] = y0; pw[3] = y1;
            pa[m] = *(bf16x8*)&pw;
        }
        bf16x8 vf[4];
#pragma unroll
        for (int n = 0; n < 4; ++n) {
            int e = n * 16 + r;
            vf[n] = *(const bf16x8*)&sm[16384 + e * 256 + (((c * 4 + g) ^ (r & 7)) << 3)];
        }
        __builtin_amdgcn_s_setprio(1);
#pragma unroll
        for (int m = 0; m < 2; ++m)
#pragma unroll
            for (int n = 0; n < 4; ++n)
                acco[m][n] = mfma16(vf[n], pa[m], acco[m][n]);  // col=s, rows=e
        __builtin_amdgcn_s_setprio(0);
    }

    // write attention output as (b, s, c=h*64+e) bf16, 8B per store
#pragma unroll
    for (int m = 0; m < 2; ++m) {
        const size_t rowb = ((size_t)(b * S_ + sw + m * 16 + r)) * C_ + h * 64;
#pragma unroll
        for (int n = 0; n < 4; ++n) {
            u32 w0 = cvtpk(acco[m][n][0], acco[m][n][1]);
            u32 w1 = cvtpk(acco[m][n][2], acco[m][n][3]);
            *(uint2*)&ao[rowb + n * 16 + g * 4] = make_uint2(w0, w1);
        }
    }
}

// ---------------------------------------------------------------- launch
extern "C" void kernel_launch(void* const* d_in, const int* in_sizes, int n_in,
                              void* d_out, int out_size, void* d_ws, size_t ws_size,
                              hipStream_t stream)
{
    (void)in_sizes; (void)n_in; (void)out_size; (void)ws_size;
    const float* x    = (const float*)d_in[0];
    const float* ctx  = (const float*)d_in[1];
    const float* gn_w = (const float*)d_in[2];
    const float* gn_b = (const float*)d_in[3];
    const float* ln_w = (const float*)d_in[4];
    const float* ln_b = (const float*)d_in[5];
    const float* q_w  = (const float*)d_in[6];
    const float* q_b  = (const float*)d_in[7];
    const float* k_w  = (const float*)d_in[8];
    const float* k_b  = (const float*)d_in[9];
    const float* v_w  = (const float*)d_in[10];
    const float* v_b  = (const float*)d_in[11];
    const float* p_w  = (const float*)d_in[12];
    const float* p_b  = (const float*)d_in[13];
    float* out = (float*)d_out;

    char* ws = (char*)d_ws;
    constexpr size_t WS_WQ   = 0;
    constexpr size_t WS_WK   = WS_WQ + (size_t)512 * 512 * 2;
    constexpr size_t WS_WV   = WS_WK + (size_t)512 * 768 * 2;
    constexpr size_t WS_WP   = WS_WV + (size_t)512 * 768 * 2;
    constexpr size_t WS_PART = WS_WP + (size_t)512 * 512 * 2;
    constexpr size_t WS_STAT = WS_PART + (size_t)16 * 64 * 2 * 4;
    constexpr size_t WS_CTXN = WS_STAT + 256;
    constexpr size_t WS_K    = WS_CTXN + (size_t)512 * 768 * 2;
    constexpr size_t WS_V    = WS_K + (size_t)2 * 8 * 256 * 64 * 2;
    constexpr size_t WS_Q    = WS_V + (size_t)2 * 8 * 256 * 64 * 2;
    constexpr size_t WS_H    = WS_Q + (size_t)2 * 32768 * 512 * 2;

    u16* wq = (u16*)(ws + WS_WQ);
    u16* wk = (u16*)(ws + WS_WK);
    u16* wv = (u16*)(ws + WS_WV);
    u16* wp = (u16*)(ws + WS_WP);
    float* part  = (float*)(ws + WS_PART);
    float* stats = (float*)(ws + WS_STAT);
    u16* ctxn = (u16*)(ws + WS_CTXN);
    u16* kt   = (u16*)(ws + WS_K);
    u16* vt   = (u16*)(ws + WS_V);
    u16* qt   = (u16*)(ws + WS_Q);
    u16* ht   = (u16*)(ws + WS_H);
    u16* ao   = ht;  // h dead after Q-GEMM; reuse for attention output

    const size_t bsc = (size_t)S_ * C_;  // per-batch (s,c)/(c,s) stride

    cvt_w<<<dim3(384, 4), 256, 0, stream>>>(q_w, k_w, v_w, p_w, wq, wk, wv, wp);
    gn_partial<<<dim3(32, 16), 256, 0, stream>>>(x, part);
    gn_final<<<16, 64, 0, stream>>>(part, stats);
    gn_apply<<<dim3(512, 8, 2), 256, 0, stream>>>(x, stats, gn_w, gn_b, ht);
    ln_ctx<<<512, 256, 0, stream>>>(ctx, ln_w, ln_b, ctxn);
    // Q = h . Wq^T (scale folded), out (b,s,o) bf16. SWAP grid: consecutive
    // ids share the ht m-tile -> same XCD after swizzle.
    gemm_nt<0, true><<<dim3(4, 256, 2), 256, 0, stream>>>(
        ht, wq, q_b, qt, nullptr, 512, 512, bsc, 0, bsc, 0.125f,
        nullptr, nullptr, nullptr);
    // K,V = ctxn . W^T in one launch (z selects)
    gemm_nt<3, false><<<dim3(4, 4, 2), 256, 0, stream>>>(
        ctxn, wk, k_b, kt, nullptr, 768, 512, 0, 0, 0, 1.0f,
        wv, v_b, vt);
    attn_kernel<<<dim3(256, 16), 256, 0, stream>>>(qt, kt, vt, ao);
    // out = Wp . ao^T + bias + x (fp32, (b,c,s)). Consecutive ids share the
    // ao n-tile -> same XCD after swizzle.
    gemm_nt<2, false><<<dim3(4, 256, 2), 256, 0, stream>>>(
        wp, ao, p_b, out, x, 512, S_, 0, bsc, bsc, 1.0f,
        nullptr, nullptr, nullptr);
}

// Round 7
// 273.648 us; speedup vs baseline: 1.6918x; 1.0310x over previous
//
#include <hip/hip_runtime.h>

typedef unsigned short u16;
typedef unsigned int u32;
typedef __attribute__((ext_vector_type(4))) float f32x4;
typedef __attribute__((ext_vector_type(8))) short bf16x8;
typedef __attribute__((ext_vector_type(8))) u16 u16x8;
typedef __attribute__((ext_vector_type(4))) u16 u16x4;
typedef __attribute__((ext_vector_type(4))) u32 u32x4;

#define DEVI __device__ __forceinline__

constexpr int C_ = 512, S_ = 32768, L_ = 256, CTX_ = 768;

DEVI u16 f2b(float f) {  // fp32 -> bf16 RNE
    union { float f; unsigned u; } x; x.f = f;
    unsigned r = x.u + 0x7fffu + ((x.u >> 16) & 1u);
    return (u16)(r >> 16);
}

DEVI f32x4 mfma16(bf16x8 a, bf16x8 b, f32x4 c) {
    return __builtin_amdgcn_mfma_f32_16x16x32_bf16(a, b, c, 0, 0, 0);
}

DEVI void gload16(const void* g, void* l) {
    __builtin_amdgcn_global_load_lds(
        (const __attribute__((address_space(1))) void*)g,
        (__attribute__((address_space(3))) void*)l, 16, 0, 0);
}

DEVI u32 cvtpk(float lo, float hi) {  // word = (bf16(hi)<<16) | bf16(lo)
    u32 d;
    asm("v_cvt_pk_bf16_f32 %0, %1, %2" : "=v"(d) : "v"(lo), "v"(hi));
    return d;
}
DEVI void pl32(u32& a, u32& b) {
    asm volatile("v_permlane32_swap_b32 %0, %1" : "+v"(a), "+v"(b));
}
DEVI void pl16(u32& a, u32& b) {
    asm volatile("v_permlane16_swap_b32 %0, %1" : "+v"(a), "+v"(b));
}

// ---------------------------------------------------------------- weights cvt
__global__ __launch_bounds__(256) void cvt_w(
    const float* __restrict__ a0, const float* __restrict__ a1,
    const float* __restrict__ a2, const float* __restrict__ a3,
    u16* __restrict__ o0, u16* __restrict__ o1,
    u16* __restrict__ o2, u16* __restrict__ o3)
{
    int which = blockIdx.y;
    const float* src = which == 0 ? a0 : which == 1 ? a1 : which == 2 ? a2 : a3;
    u16* dst = which == 0 ? o0 : which == 1 ? o1 : which == 2 ? o2 : o3;
    int n4 = (which == 1 || which == 2) ? (512 * 768 / 4) : (512 * 512 / 4);
    int i = blockIdx.x * 256 + threadIdx.x;
    if (i < n4) {
        float4 v = ((const float4*)src)[i];
        u16x4 o; o[0] = f2b(v.x); o[1] = f2b(v.y); o[2] = f2b(v.z); o[3] = f2b(v.w);
        ((u16x4*)dst)[i] = o;
    }
}

// ---------------------------------------------------------------- GN stats
__global__ __launch_bounds__(256) void gn_partial(const float* __restrict__ x,
                                                  float* __restrict__ part)
{
    const int bg = blockIdx.y, blk = blockIdx.x, tid = threadIdx.x;
    const float* base = x + (size_t)bg * 64 * S_ + (size_t)blk * 1024 + tid * 4;
    float s1 = 0.f, s2 = 0.f;
    for (int c = 0; c < 64; ++c) {
        float4 v = *(const float4*)(base + (size_t)c * S_);
        s1 += v.x + v.y + v.z + v.w;
        s2 += v.x * v.x + v.y * v.y + v.z * v.z + v.w * v.w;
    }
    for (int m = 1; m < 64; m <<= 1) { s1 += __shfl_xor(s1, m); s2 += __shfl_xor(s2, m); }
    __shared__ float a1[4], a2[4];
    int w = tid >> 6, lane = tid & 63;
    if (lane == 0) { a1[w] = s1; a2[w] = s2; }
    __syncthreads();
    if (tid == 0) {
        part[(bg * 32 + blk) * 2 + 0] = a1[0] + a1[1] + a1[2] + a1[3];
        part[(bg * 32 + blk) * 2 + 1] = a2[0] + a2[1] + a2[2] + a2[3];
    }
}

__global__ __launch_bounds__(64) void gn_final(const float* __restrict__ part,
                                               float* __restrict__ stats)
{
    int bg = blockIdx.x, tid = threadIdx.x;
    float s1 = tid < 32 ? part[(bg * 32 + tid) * 2] : 0.f;
    float s2 = tid < 32 ? part[(bg * 32 + tid) * 2 + 1] : 0.f;
    for (int m = 1; m < 32; m <<= 1) { s1 += __shfl_xor(s1, m); s2 += __shfl_xor(s2, m); }
    if (tid == 0) {
        const float invN = 1.0f / (64.0f * (float)S_);
        float mu = s1 * invN, var = s2 * invN - mu * mu;
        stats[bg * 2] = mu;
        stats[bg * 2 + 1] = rsqrtf(var + 1e-5f);
    }
}

// per-(batch,c) fused GN coefficients: xn = x*ca + cb
__global__ __launch_bounds__(256) void gn_coef(
    const float* __restrict__ stats, const float* __restrict__ gw,
    const float* __restrict__ gb, float* __restrict__ ca, float* __restrict__ cb)
{
    int i = blockIdx.x * 256 + threadIdx.x;  // 0..1023
    int z = i >> 9, c = i & 511;
    int bg = z * 8 + (c >> 6);
    float mu = stats[bg * 2], rs = stats[bg * 2 + 1];
    float a = rs * gw[c];
    ca[i] = a;
    cb[i] = gb[c] - mu * a;
}

// ---------------------------------------------------------------- LayerNorm(ctx)
__global__ __launch_bounds__(256) void ln_ctx(
    const float* __restrict__ ctx, const float* __restrict__ lw,
    const float* __restrict__ lb, u16* __restrict__ cn)
{
    const int row = blockIdx.x, tid = threadIdx.x;
    const float* p = ctx + (size_t)row * CTX_;
    float v0 = p[tid], v1 = p[tid + 256], v2 = p[tid + 512];
    float s1 = v0 + v1 + v2, s2 = v0 * v0 + v1 * v1 + v2 * v2;
    for (int m = 1; m < 64; m <<= 1) { s1 += __shfl_xor(s1, m); s2 += __shfl_xor(s2, m); }
    __shared__ float a1[4], a2[4];
    int w = tid >> 6, lane = tid & 63;
    if (lane == 0) { a1[w] = s1; a2[w] = s2; }
    __syncthreads();
    s1 = a1[0] + a1[1] + a1[2] + a1[3];
    s2 = a2[0] + a2[1] + a2[2] + a2[3];
    const float invN = 1.0f / 768.0f;
    float mu = s1 * invN, rstd = rsqrtf(s2 * invN - mu * mu + 1e-5f);
    u16* o = cn + (size_t)row * CTX_;
    o[tid]       = f2b((v0 - mu) * rstd * lw[tid]       + lb[tid]);
    o[tid + 256] = f2b((v1 - mu) * rstd * lw[tid + 256] + lb[tid + 256]);
    o[tid + 512] = f2b((v2 - mu) * rstd * lw[tid + 512] + lb[tid + 512]);
}

// ---------------------------------------------------------------- NT-GEMM
// acc = mfma(Bfrag, Afrag): col(lane&15) = m-row, rows(g*4+i) = n-rows.
// Double-buffered (32KB LDS), 1 barrier/iter, XCD-swizzled grid.
// SWAP: m-tile from blockIdx.y (consecutive ids share the A m-tile).
// LDS logical (mrow, k): u16 idx = (mrow>>1)*64
//      + ((((mrow&1)*4)+(k>>3)) ^ ((mrow>>1)&7))*8 + (k&7)
// MODE 0: bf16 out[m*ldo + n..n+3] = (acc + bias[n]) * scale   (uint2)
// MODE 2: f32  out[m*ldo + n..n+3] = acc + bias[m] + resid     (float4)
// MODE 3: z==0 -> like MODE0 to outp (K proj); z==1 -> V-scatter to outp2
// MODE 4: A = x fp32 (c,s) with fused GroupNorm (resid=x, bias2=coefA,
//         outp2=coefB); transposing bf16 staging in-kernel; MODE0 epilogue.
template <int MODE, bool SWAP>
__global__ __launch_bounds__(256, 4) void gemm_nt(
    const u16* __restrict__ A, const u16* __restrict__ Bp,
    const float* __restrict__ bias, void* __restrict__ outp,
    const float* __restrict__ resid, int K, int ldo,
    size_t aStride, size_t bStride, size_t oStride, float scale,
    const u16* __restrict__ Bp2, const float* __restrict__ bias2,
    void* __restrict__ outp2)
{
    __shared__ __align__(16) u16 lA[2][4096];
    __shared__ __align__(16) u16 lB[2][4096];
    const int tid = threadIdx.x;
    const int w = tid >> 6, lane = tid & 63;
    const int g = lane >> 4, r = lane & 15;

    // XCD-aware bijective swizzle of the per-z (x,y) grid (nxy % 8 == 0).
    const int nx = gridDim.x, nxy = nx * gridDim.y;
    const int raw = blockIdx.x + nx * blockIdx.y;
    const int tile = (raw & 7) * (nxy >> 3) + (raw >> 3);
    const int bx = tile % nx, by = tile / nx;
    const int m0 = (SWAP ? by : bx) * 128, n0 = (SWAP ? bx : by) * 128;
    const int z = blockIdx.z;
    A += (size_t)z * aStride;
    const u16* Bsel = Bp;
    if constexpr (MODE == 3) { if (z) Bsel = Bp2; }
    Bsel += (size_t)z * bStride;

    // staging source pre-swizzle (rule #21: linear LDS dest, permuted source)
    const int l8 = lane & 7, lh = lane >> 3;
    const int u_ = l8 ^ lh;                 // slot-at-dest ^ row&7
    const int mro = (lh << 1) + (u_ >> 2);  // row offset within 16-row chunk
    const int kco = (u_ & 3) * 8;           // k offset (elements) within 32
    const int wr = w >> 1, wc = w & 1;
    const int nt = K >> 5;

    f32x4 acc[4][4];
#pragma unroll
    for (int m = 0; m < 4; ++m)
#pragma unroll
        for (int n = 0; n < 4; ++n) acc[m][n] = f32x4{0.f, 0.f, 0.f, 0.f};

#define STAGE_B(t, bi_) {                                                      \
    size_t ko_ = (size_t)((t) * 32 + kco);                                     \
    _Pragma("unroll")                                                          \
    for (int j = 0; j < 2; ++j) {                                              \
        int grow_ = w * 32 + j * 16 + mro;                                     \
        gload16(Bsel + (size_t)(n0 + grow_) * K + ko_,                         \
                &lB[bi_][(w * 16 + j * 8) << 6]);                              \
    } }

#define STAGE_A(t, bi_) {                                                      \
    size_t ko_ = (size_t)((t) * 32 + kco);                                     \
    _Pragma("unroll")                                                          \
    for (int j = 0; j < 2; ++j) {                                              \
        int grow_ = w * 32 + j * 16 + mro;                                     \
        gload16(A + (size_t)(m0 + grow_) * K + ko_,                            \
                &lA[bi_][(w * 16 + j * 8) << 6]);                              \
    } }

    // MODE4 state: fused-GN transposing A staging
    const float* xA = nullptr;
    const float* cAp = nullptr;
    const float* cBp = nullptr;
    int cp2 = 0, sb = 0, zc = 0;
    f32x4 a00{}, a01{}, a10{}, a11{};
    float2 ka{}, kb{};
    if constexpr (MODE == 4) {
        xA = resid + (size_t)z * ((size_t)C_ * S_);
        cAp = bias2;
        cBp = (const float*)outp2;
        cp2 = (tid >> 4) * 2;       // c-pair base within 32-chunk
        sb = (tid & 15) * 8;        // 8 consecutive s
        zc = z * 512;
    }

#define LOAD_A4(t) {                                                           \
    int c0n_ = (t) * 32 + cp2;                                                 \
    const float* r0_ = xA + (size_t)c0n_ * S_ + m0 + sb;                       \
    a00 = *(const f32x4*)r0_;  a01 = *(const f32x4*)(r0_ + 4);                 \
    a10 = *(const f32x4*)(r0_ + S_); a11 = *(const f32x4*)(r0_ + S_ + 4);      \
    ka = *(const float2*)&cAp[zc + c0n_];                                      \
    kb = *(const float2*)&cBp[zc + c0n_]; }

#define WRITE_A4(bi_) {                                                        \
    _Pragma("unroll")                                                          \
    for (int j = 0; j < 8; ++j) {                                              \
        float v0_ = ((j < 4) ? a00[j] : a01[j - 4]) * ka.x + kb.x;             \
        float v1_ = ((j < 4) ? a10[j] : a11[j - 4]) * ka.y + kb.y;             \
        int mm_ = sb + j;                                                      \
        int idx_ = ((mm_ >> 1) << 6)                                           \
            + (((((mm_ & 1) << 2) + (cp2 >> 3)) ^ ((mm_ >> 1) & 7)) << 3)      \
            + (cp2 & 7);                                                       \
        *(u32*)&lA[bi_][idx_] = cvtpk(v0_, v1_);                               \
    } }

    if constexpr (MODE == 4) {
        STAGE_B(0, 0);
        LOAD_A4(0);
        WRITE_A4(0);
    } else {
        STAGE_A(0, 0);
        STAGE_B(0, 0);
    }
    __syncthreads();

    for (int t = 0; t < nt; ++t) {
        const int cur = t & 1;
        if (t + 1 < nt) {
            STAGE_B(t + 1, cur ^ 1);
            if constexpr (MODE == 4) { LOAD_A4(t + 1); }
            else                     { STAGE_A(t + 1, cur ^ 1); }
        }
        bf16x8 af[4], bf_[4];
#pragma unroll
        for (int m = 0; m < 4; ++m) {
            int row = wr * 32 + m * 8 + (r >> 1);
            int slot = (((r & 1) << 2) + g) ^ ((r >> 1) & 7);
            af[m] = *(const bf16x8*)&lA[cur][(row << 6) + (slot << 3)];
        }
#pragma unroll
        for (int n = 0; n < 4; ++n) {
            int row = wc * 32 + n * 8 + (r >> 1);
            int slot = (((r & 1) << 2) + g) ^ ((r >> 1) & 7);
            bf_[n] = *(const bf16x8*)&lB[cur][(row << 6) + (slot << 3)];
        }
#pragma unroll
        for (int m = 0; m < 4; ++m)
#pragma unroll
            for (int n = 0; n < 4; ++n)
                acc[m][n] = mfma16(bf_[n], af[m], acc[m][n]);  // col=m, rows=n
        if constexpr (MODE == 4) { if (t + 1 < nt) WRITE_A4(cur ^ 1); }
        __syncthreads();
    }
#undef STAGE_A
#undef STAGE_B
#undef LOAD_A4
#undef WRITE_A4

    if constexpr (MODE == 0 || MODE == 4) {
        u16* ob = (u16*)outp + (size_t)z * oStride;
#pragma unroll
        for (int m = 0; m < 4; ++m) {
            int gm = m0 + wr * 64 + m * 16 + r;
#pragma unroll
            for (int n = 0; n < 4; ++n) {
                int gn0 = n0 + wc * 64 + n * 16 + g * 4;
                float4 bn = *(const float4*)&bias[gn0];
                u32 w0 = cvtpk(acc[m][n][0] * scale + bn.x * scale,
                               acc[m][n][1] * scale + bn.y * scale);
                u32 w1 = cvtpk(acc[m][n][2] * scale + bn.z * scale,
                               acc[m][n][3] * scale + bn.w * scale);
                *(uint2*)&ob[(size_t)gm * ldo + gn0] = make_uint2(w0, w1);
            }
        }
    } else if constexpr (MODE == 2) {
        float* of = (float*)outp + (size_t)z * oStride;
        const float* rs = resid + (size_t)z * oStride;
#pragma unroll
        for (int m = 0; m < 4; ++m) {
            int gm = m0 + wr * 64 + m * 16 + r;
            float bm = bias[gm];
#pragma unroll
            for (int n = 0; n < 4; ++n) {
                int gn0 = n0 + wc * 64 + n * 16 + g * 4;
                size_t idx = (size_t)gm * ldo + gn0;
                float4 rv = *(const float4*)&rs[idx];
                float4 o4;
                o4.x = acc[m][n][0] + bm + rv.x;
                o4.y = acc[m][n][1] + bm + rv.y;
                o4.z = acc[m][n][2] + bm + rv.z;
                o4.w = acc[m][n][3] + bm + rv.w;
                *(float4*)&of[idx] = o4;
            }
        }
    } else if constexpr (MODE == 3) {
        if (z == 0) {  // K projection: (b*l, o) bf16
            u16* ob = (u16*)outp;
#pragma unroll
            for (int m = 0; m < 4; ++m) {
                int gm = m0 + wr * 64 + m * 16 + r;
#pragma unroll
                for (int n = 0; n < 4; ++n) {
                    int gn0 = n0 + wc * 64 + n * 16 + g * 4;
                    float4 bn = *(const float4*)&bias[gn0];
                    u32 w0 = cvtpk(acc[m][n][0] + bn.x, acc[m][n][1] + bn.y);
                    u32 w1 = cvtpk(acc[m][n][2] + bn.z, acc[m][n][3] + bn.w);
                    *(uint2*)&ob[(size_t)gm * ldo + gn0] = make_uint2(w0, w1);
                }
            }
        } else {       // V projection scattered to (b,h,e,l) bf16
            u16* ob = (u16*)outp2;
#pragma unroll
            for (int m = 0; m < 4; ++m) {
                int gm = m0 + wr * 64 + m * 16 + r;  // ctx row = b*256 + l
                int bb = gm >> 8, l = gm & 255;
#pragma unroll
                for (int n = 0; n < 4; ++n) {
                    int gn0 = n0 + wc * 64 + n * 16 + g * 4;
#pragma unroll
                    for (int i = 0; i < 4; ++i)
                        ob[((size_t)(bb * 512 + gn0 + i)) * 256 + l] =
                            f2b(acc[m][n][i] + bias2[gn0 + i]);
                }
            }
        }
    }
}

// ---------------------------------------------------------------- attention
// Swapped-QK^T: lane holds P[s = lane&15][l in regs]. K AND V staged in LDS
// (64 KB) -- each block reads them once, coalesced; keeps L2 free for the
// Q/ao streams (R5 lesson: direct-global V thrashed L2 -> 4-8x HBM traffic).
// PV operand-swapped: output has 4 consecutive e per lane -> 8B stores.
// grid: (S/128, B*NH). block 256 (4 waves, 32 s-rows each).
__global__ __launch_bounds__(256, 2) void attn_kernel(
    const u16* __restrict__ q, const u16* __restrict__ kk,
    const u16* __restrict__ vv, u16* __restrict__ ao)
{
    __shared__ __align__(16) u16 sm[32768];
    const int tid = threadIdx.x;
    const int w = tid >> 6, lane = tid & 63;
    const int g = lane >> 4, r = lane & 15;
    const int bh = blockIdx.y, b = bh >> 3, h = bh & 7;
    const int s0 = blockIdx.x * 128;

    {   // stage K (b,l,h*64+e) rows -> sm[l*64 + swz]
        const u16* kbase = kk + ((size_t)b * L_) * C_ + h * 64;
#pragma unroll
        for (int j = 0; j < 8; ++j) {
            int idx = j * 256 + tid;
            int l = idx >> 3, ch = idx & 7;
            u16x8 val = *(const u16x8*)(kbase + (size_t)l * C_ + ch * 8);
            *(u16x8*)&sm[l * 64 + ((ch ^ (l & 7)) << 3)] = val;
        }
        // stage V (b,h,e,l) rows -> sm[16384 + e*256 + swz]
        const u16* vbase = vv + ((size_t)bh * 64) * 256;
#pragma unroll
        for (int j = 0; j < 8; ++j) {
            int idx = j * 256 + tid;
            int e = idx >> 5, ch = idx & 31;
            u16x8 val = *(const u16x8*)(vbase + (size_t)e * 256 + ch * 8);
            *(u16x8*)&sm[16384 + e * 256 + ((ch ^ (e & 7)) << 3)] = val;
        }
    }

    // Q fragments straight from global (read-once)
    const int sw = s0 + w * 32;
    bf16x8 qf[2][2];
#pragma unroll
    for (int m = 0; m < 2; ++m)
#pragma unroll
        for (int kt = 0; kt < 2; ++kt)
            qf[m][kt] = *(const bf16x8*)(q + ((size_t)(b * S_ + sw + m * 16 + r)) * C_
                                         + h * 64 + kt * 32 + g * 8);
    __syncthreads();

    // QK^T swapped: accs[m][n][i] = P[s = m*16 + r][l = n*16 + g*4 + i]
    f32x4 accs[2][16];
#pragma unroll
    for (int m = 0; m < 2; ++m)
#pragma unroll
        for (int n = 0; n < 16; ++n) accs[m][n] = f32x4{0.f, 0.f, 0.f, 0.f};
    __builtin_amdgcn_s_setprio(1);
#pragma unroll
    for (int n = 0; n < 16; ++n) {
#pragma unroll
        for (int kt = 0; kt < 2; ++kt) {
            int c = kt * 4 + g;  // e-chunk index
            bf16x8 kf = *(const bf16x8*)&sm[(n * 16 + r) * 64 + ((c ^ (r & 7)) << 3)];
#pragma unroll
            for (int m = 0; m < 2; ++m) accs[m][n] = mfma16(kf, qf[m][kt], accs[m][n]);
        }
    }
    __builtin_amdgcn_s_setprio(0);

    // softmax: in-lane over 64 values, cross-lane over the 4 lanes sharing r
    float inv[2];
#pragma unroll
    for (int m = 0; m < 2; ++m) {
        float mx = accs[m][0][0];
#pragma unroll
        for (int n = 0; n < 16; ++n)
#pragma unroll
            for (int i = 0; i < 4; ++i) mx = fmaxf(mx, accs[m][n][i]);
        mx = fmaxf(mx, __shfl_xor(mx, 16));
        mx = fmaxf(mx, __shfl_xor(mx, 32));
        float sum = 0.f;
#pragma unroll
        for (int n = 0; n < 16; ++n)
#pragma unroll
            for (int i = 0; i < 4; ++i) {
                float e = __expf(accs[m][n][i] - mx);
                accs[m][n][i] = e; sum += e;
            }
        sum += __shfl_xor(sum, 16);
        sum += __shfl_xor(sum, 32);
        inv[m] = 1.0f / sum;
    }

    // PV: per l-chunk c, repack P in-register into fragments, then MFMA.
    // Operand-swapped: acco[m][n]: col(r) = s, rows(g*4+i) = e.
    f32x4 acco[2][4];
#pragma unroll
    for (int m = 0; m < 2; ++m)
#pragma unroll
        for (int n = 0; n < 4; ++n) acco[m][n] = f32x4{0.f, 0.f, 0.f, 0.f};

#pragma unroll
    for (int c = 0; c < 8; ++c) {
        bf16x8 pa[2];
#pragma unroll
        for (int m = 0; m < 2; ++m) {
            u32 x0 = cvtpk(accs[m][2 * c][0] * inv[m], accs[m][2 * c][1] * inv[m]);
            u32 x1 = cvtpk(accs[m][2 * c][2] * inv[m], accs[m][2 * c][3] * inv[m]);
            u32 y0 = cvtpk(accs[m][2 * c + 1][0] * inv[m], accs[m][2 * c + 1][1] * inv[m]);
            u32 y1 = cvtpk(accs[m][2 * c + 1][2] * inv[m], accs[m][2 * c + 1][3] * inv[m]);
            pl32(x0, y0);
            pl32(x1, y1);
            pl16(x0, y0);
            pl16(x1, y1);
            u32x4 pw; pw[0] = x0; pw[1] = x1; pw[2] = y0; pw[3] = y1;
            pa[m] = *(bf16x8*)&pw;
        }
        bf16x8 vf[4];
#pragma unroll
        for (int n = 0; n < 4; ++n) {
            int e = n * 16 + r;
            vf[n] = *(const bf16x8*)&sm[16384 + e * 256 + (((c * 4 + g) ^ (r & 7)) << 3)];
        }
        __builtin_amdgcn_s_setprio(1);
#pragma unroll
        for (int m = 0; m < 2; ++m)
#pragma unroll
            for (int n = 0; n < 4; ++n)
                acco[m][n] = mfma16(vf[n], pa[m], acco[m][n]);  // col=s, rows=e
        __builtin_amdgcn_s_setprio(0);
    }

    // write attention output as (b, s, c=h*64+e) bf16, 8B per store
#pragma unroll
    for (int m = 0; m < 2; ++m) {
        const size_t rowb = ((size_t)(b * S_ + sw + m * 16 + r)) * C_ + h * 64;
#pragma unroll
        for (int n = 0; n < 4; ++n) {
            u32 w0 = cvtpk(acco[m][n][0], acco[m][n][1]);
            u32 w1 = cvtpk(acco[m][n][2], acco[m][n][3]);
            *(uint2*)&ao[rowb + n * 16 + g * 4] = make_uint2(w0, w1);
        }
    }
}

// ---------------------------------------------------------------- launch
extern "C" void kernel_launch(void* const* d_in, const int* in_sizes, int n_in,
                              void* d_out, int out_size, void* d_ws, size_t ws_size,
                              hipStream_t stream)
{
    (void)in_sizes; (void)n_in; (void)out_size; (void)ws_size;
    const float* x    = (const float*)d_in[0];
    const float* ctx  = (const float*)d_in[1];
    const float* gn_w = (const float*)d_in[2];
    const float* gn_b = (const float*)d_in[3];
    const float* ln_w = (const float*)d_in[4];
    const float* ln_b = (const float*)d_in[5];
    const float* q_w  = (const float*)d_in[6];
    const float* q_b  = (const float*)d_in[7];
    const float* k_w  = (const float*)d_in[8];
    const float* k_b  = (const float*)d_in[9];
    const float* v_w  = (const float*)d_in[10];
    const float* v_b  = (const float*)d_in[11];
    const float* p_w  = (const float*)d_in[12];
    const float* p_b  = (const float*)d_in[13];
    float* out = (float*)d_out;

    char* ws = (char*)d_ws;
    constexpr size_t WS_WQ   = 0;
    constexpr size_t WS_WK   = WS_WQ + (size_t)512 * 512 * 2;
    constexpr size_t WS_WV   = WS_WK + (size_t)512 * 768 * 2;
    constexpr size_t WS_WP   = WS_WV + (size_t)512 * 768 * 2;
    constexpr size_t WS_PART = WS_WP + (size_t)512 * 512 * 2;
    constexpr size_t WS_STAT = WS_PART + (size_t)16 * 64 * 2 * 4;
    constexpr size_t WS_CA   = WS_STAT + 256;
    constexpr size_t WS_CB   = WS_CA + 4096;
    constexpr size_t WS_CTXN = WS_CB + 4096;
    constexpr size_t WS_K    = WS_CTXN + (size_t)512 * 768 * 2;
    constexpr size_t WS_V    = WS_K + (size_t)2 * 8 * 256 * 64 * 2;
    constexpr size_t WS_Q    = WS_V + (size_t)2 * 8 * 256 * 64 * 2;
    constexpr size_t WS_H    = WS_Q + (size_t)2 * 32768 * 512 * 2;

    u16* wq = (u16*)(ws + WS_WQ);
    u16* wk = (u16*)(ws + WS_WK);
    u16* wv = (u16*)(ws + WS_WV);
    u16* wp = (u16*)(ws + WS_WP);
    float* part  = (float*)(ws + WS_PART);
    float* stats = (float*)(ws + WS_STAT);
    float* coefA = (float*)(ws + WS_CA);
    float* coefB = (float*)(ws + WS_CB);
    u16* ctxn = (u16*)(ws + WS_CTXN);
    u16* kt   = (u16*)(ws + WS_K);
    u16* vt   = (u16*)(ws + WS_V);
    u16* qt   = (u16*)(ws + WS_Q);
    u16* ao   = (u16*)(ws + WS_H);  // attention output buffer

    const size_t bsc = (size_t)S_ * C_;  // per-batch (s,c)/(c,s) stride

    cvt_w<<<dim3(384, 4), 256, 0, stream>>>(q_w, k_w, v_w, p_w, wq, wk, wv, wp);
    gn_partial<<<dim3(32, 16), 256, 0, stream>>>(x, part);
    gn_final<<<16, 64, 0, stream>>>(part, stats);
    gn_coef<<<4, 256, 0, stream>>>(stats, gn_w, gn_b, coefA, coefB);
    ln_ctx<<<512, 256, 0, stream>>>(ctx, ln_w, ln_b, ctxn);
    // Q = GN(x) . Wq^T fused (scale folded), out (b,s,o) bf16. SWAP grid:
    // consecutive ids share the x s-tile -> same XCD after swizzle.
    gemm_nt<4, true><<<dim3(4, 256, 2), 256, 0, stream>>>(
        nullptr, wq, q_b, qt, x, 512, 512, 0, 0, bsc, 0.125f,
        nullptr, coefA, coefB);
    // K,V = ctxn . W^T in one launch (z selects)
    gemm_nt<3, false><<<dim3(4, 4, 2), 256, 0, stream>>>(
        ctxn, wk, k_b, kt, nullptr, 768, 512, 0, 0, 0, 1.0f,
        wv, v_b, vt);
    attn_kernel<<<dim3(256, 16), 256, 0, stream>>>(qt, kt, vt, ao);
    // out = Wp . ao^T + bias + x (fp32, (b,c,s)). Consecutive ids share the
    // ao n-tile -> same XCD after swizzle.
    gemm_nt<2, false><<<dim3(4, 256, 2), 256, 0, stream>>>(
        wp, ao, p_b, out, x, 512, S_, 0, bsc, bsc, 1.0f,
        nullptr, nullptr, nullptr);
}